// Round 9
// baseline (17.460 us; speedup 1.0000x reference)
//
#include <hip/hip_runtime.h>
#include <hip/hip_bf16.h>
#include <string.h>

// TaylorLayer via MFMA: out[B,8] = relu(W[8,164] @ epd[164,B] + b), B=262144.
// epd = monomials deg 1..3 of x[8], reference recursion order, T=164.
//
// Measured: true kernel ~5.8us, fixed harness overhead ~10.5us (R6), of
// which ~2-3us is the prep_w graph node (exec + inter-node gap).
// R9: SINGLE kernel. Each block builds the sigma-permuted bf16 W fragment
// table in its own LDS (11264B, 22 gathers/thread from L2-hot 5.2KB W,
// one barrier); A-fragments then come from ds_read_b128 (1/step/wave,
// hidden under VALU). Bias folded into MFMA: pad slot 84 = constant-1
// monomial, W column = b in half0 / 0 in half1 -> no b load, no epilogue
// adds. d_ws unused.
//
// Sigma trick (R7): involution s(j)=j^4 maps the monomial set to itself;
// half-1 lanes run the IDENTICAL slot program on sigma-permuted inputs,
// absorbed into load addressing (R8). W permuted to match via TDX table.
//
// MFMA mfma_f32_32x32x16_bf16, K=176. A: row=lane&31 (rows 8..31 zero),
// half h=lane>>5, slot 8i+j. B: col=lane&31, same k-map. C/D: col=lane&31,
// row=(reg&3)+8*(reg>>2)+4*(lane>>5) -> regs 0..3 = rows 4h+0..3.

static constexpr int TEXP = 164;
static constexpr int NOUT = 8;
static constexpr int NMFMA = 11;   // K = 176
static constexpr int NSLOT = 88;   // slots per k-half
static constexpr int BIAS_T = 200; // marker: W entry = bias[row]
static constexpr int NWP = NMFMA * 64 * 8;  // 5632 fragment entries

using f32x16 = __attribute__((ext_vector_type(16))) float;
using short8 = __attribute__((ext_vector_type(8))) short;

// ---- reference t-order index math ----
constexpr int rowstart2(int j) { return j * 8 - j * (j - 1) / 2; }
constexpr int start3(int j) {
  int s = 44;
  for (int jp = 0; jp < j; ++jp) s += (8 - jp) * (9 - jp) / 2;
  return s;
}
constexpr int t3_of(int a, int b, int c) {
  int x = a, y = b, z = c, t = 0;
  if (x > y) { t = x; x = y; y = t; }
  if (y > z) { t = y; y = z; z = t; }
  if (x > y) { t = x; x = y; y = t; }
  int off = 0;
  for (int ap = x; ap < y; ++ap) off += 8 - ap;
  return start3(x) + off + (z - y);
}

// ---- slot table: 84 half-0 representatives (>=2 low indices) + 4 pads ----
struct Slot { int deg, a, b, c; };
struct SlotTable { Slot s[NSLOT]; };

constexpr bool isrep2(int j, int k) {      // j<=k
  if (k < 4) return true;
  if (j >= 4) return false;
  if (k == j + 4) return true;             // fixed (dup; W zero in half1)
  return j < k - 4;
}
constexpr bool isrep3(int a, int b, int c) {
  return ((a < 4) + (b < 4) + (c < 4)) >= 2;
}

constexpr SlotTable make_slots() {
  SlotTable T{};
  int s = 0;
  for (int j = 0; j < 4; ++j) T.s[s++] = {1, j, 0, 0};                 // 4
  for (int j = 0; j < 8; ++j)
    for (int k = j; k < 8; ++k)
      if (isrep2(j, k)) T.s[s++] = {2, j, k, 0};                       // 20
  for (int a = 0; a < 8; ++a)
    for (int b = a; b < 8; ++b)
      for (int c = b; c < 8; ++c)
        if (isrep3(a, b, c)) T.s[s++] = {3, a, b, c};                  // 60
  for (; s < NSLOT; ++s) T.s[s] = {0, 0, 0, 0};                        // pads 84..87
  return T;
}
constexpr SlotTable SLOTS = make_slots();

// ---- per-(half,slot) -> reference t index; -1 => W=0; BIAS_T => b[row] ----
struct TT { short t[2][NSLOT]; };
constexpr TT make_tt() {
  TT r{};
  for (int h = 0; h < 2; ++h)
    for (int s = 0; s < NSLOT; ++s) {
      Slot sl = SLOTS.s[s];
      int m = h ? 4 : 0;
      if (sl.deg == 0) {
        r.t[h][s] = (short)((h == 0 && s == 84) ? BIAS_T : -1);  // bias slot
      } else if (sl.deg == 1) {
        r.t[h][s] = (short)(sl.a ^ m);
      } else if (sl.deg == 2) {
        if (h == 1 && sl.b == (sl.a ^ 4)) { r.t[h][s] = -1; }    // dup-fixed
        else {
          int a = sl.a ^ m, b = sl.b ^ m;
          int lo = a < b ? a : b, hi2 = a < b ? b : a;
          r.t[h][s] = (short)(8 + rowstart2(lo) + (hi2 - lo));
        }
      } else {
        r.t[h][s] = (short)t3_of(sl.a ^ m, sl.b ^ m, sl.c ^ m);
      }
    }
  return r;
}
__device__ const TT TDX = make_tt();

__device__ __forceinline__ unsigned short bf16rne(float v) {
  union { float f; unsigned int u; } c; c.f = v;
  unsigned int u = c.u;
  return (unsigned short)((u + 0x7fffu + ((u >> 16) & 1u)) >> 16);
}

// slot value from sigma-permuted inputs xs and d2 over xs (rows j<4).
// slot 84 is the constant-1 bias monomial (both halves; half1 W = 0).
template <int S>
__device__ __forceinline__ float slotval(const float (&xs)[8], const float (&d2)[36]) {
  constexpr int deg = SLOTS.s[S].deg;
  constexpr int a = SLOTS.s[S].a;
  constexpr int b = SLOTS.s[S].b;
  constexpr int c = SLOTS.s[S].c;
  if constexpr (deg == 1) return xs[a];
  else if constexpr (deg == 2) return d2[rowstart2(a) + (b - a)];         // a < 4
  else if constexpr (deg == 3) return xs[a] * d2[rowstart2(b) + (c - b)]; // b < 4
  else if constexpr (S == 84) return 1.0f;                                 // bias
  else return 0.0f;
}

template <int I>
struct MfmaStep {
  static __device__ __forceinline__ void run(const float (&xs)[8], const float (&d2)[36],
                                             const unsigned short* wlds_lane,
                                             short8 af_cur, f32x16& acc) {
    short8 af_next;
    if constexpr (I + 1 < NMFMA)
      af_next = *reinterpret_cast<const short8*>(wlds_lane + (I + 1) * 64 * 8);
    short8 bv;
    bv[0] = (short)bf16rne(slotval<8 * I + 0>(xs, d2));
    bv[1] = (short)bf16rne(slotval<8 * I + 1>(xs, d2));
    bv[2] = (short)bf16rne(slotval<8 * I + 2>(xs, d2));
    bv[3] = (short)bf16rne(slotval<8 * I + 3>(xs, d2));
    bv[4] = (short)bf16rne(slotval<8 * I + 4>(xs, d2));
    bv[5] = (short)bf16rne(slotval<8 * I + 5>(xs, d2));
    bv[6] = (short)bf16rne(slotval<8 * I + 6>(xs, d2));
    bv[7] = (short)bf16rne(slotval<8 * I + 7>(xs, d2));
    acc = __builtin_amdgcn_mfma_f32_32x32x16_bf16(af_cur, bv, acc, 0, 0, 0);
    if constexpr (I + 1 < NMFMA)
      MfmaStep<I + 1>::run(xs, d2, wlds_lane, af_next, acc);
  }
};

__global__ __launch_bounds__(256, 4) void taylor_mfma(
    const float* __restrict__ x, const float* __restrict__ W,
    const float* __restrict__ b, float* __restrict__ out, int ngroups) {
  __shared__ __align__(16) unsigned short wlds[NWP];  // 11264 B

  // ---- per-block prep: sigma-permuted bf16 W fragments into LDS ----
  // wlds[(i*64+lane)*8 + j] = bf16(W[row][TDX[h][8i+j]]); row=lane&31
  // (>=8 -> 0), h=lane>>5; BIAS_T -> b[row]; -1 -> 0. W is 5.2KB, L2-hot.
  for (int k = (int)threadIdx.x; k < NWP; k += 256) {
    int j = k & 7;
    int lane = (k >> 3) & 63;
    int i = k >> 9;
    int row = lane & 31, h = lane >> 5;
    int t = TDX.t[h][8 * i + j];
    float v = 0.0f;
    if (row < NOUT) {
      if (t >= 0 && t < TEXP) v = W[row * TEXP + t];
      else if (t == BIAS_T) v = b[row];
    }
    wlds[k] = bf16rne(v);
  }
  __syncthreads();

  const int lane = (int)(threadIdx.x & 63);
  const int h = (lane >= 32) ? 1 : 0;
  const int col = lane & 31;

  const int g = (int)((blockIdx.x * blockDim.x + threadIdx.x) >> 6);
  if (g >= ngroups) return;
  const int elem = g * 32 + col;

  // sigma absorbed into addressing: h=0 identity, h=1 swaps float4 halves
  const float* xe = x + elem * 8;
  float4 fA = *reinterpret_cast<const float4*>(xe + 4 * h);
  float4 fB = *reinterpret_cast<const float4*>(xe + 4 - 4 * h);
  float xs[8] = {fA.x, fA.y, fA.z, fA.w, fB.x, fB.y, fB.z, fB.w};

  const unsigned short* wlds_lane = wlds + lane * 8;
  short8 af0 = *reinterpret_cast<const short8*>(wlds_lane);

  // d2 over xs, rows j<4 only (all slot reps have a low pair-lead)
  float d2[36];
#pragma unroll
  for (int j = 0; j < 4; ++j) {
#pragma unroll
    for (int k = j; k < 8; ++k) {
      d2[rowstart2(j) + (k - j)] = xs[j] * xs[k];
    }
  }

  f32x16 acc;
#pragma unroll
  for (int r = 0; r < 16; ++r) acc[r] = 0.0f;

  MfmaStep<0>::run(xs, d2, wlds_lane, af0, acc);

  float4 o;  // bias already accumulated via slot 84
  o.x = fmaxf(acc[0], 0.0f);
  o.y = fmaxf(acc[1], 0.0f);
  o.z = fmaxf(acc[2], 0.0f);
  o.w = fmaxf(acc[3], 0.0f);
  *reinterpret_cast<float4*>(out + elem * 8 + 4 * h) = o;
}

extern "C" void kernel_launch(void* const* d_in, const int* in_sizes, int n_in,
                              void* d_out, int out_size, void* d_ws, size_t ws_size,
                              hipStream_t stream) {
  const float* x = (const float*)d_in[0];   // [262144, 8, 1]
  const float* W = (const float*)d_in[1];   // [8, 164]
  const float* b = (const float*)d_in[2];   // [8, 1]
  float* out = (float*)d_out;               // [262144, 8]

  int n = in_sizes[0] / 8;      // 262144 elements
  int ngroups = n / 32;         // 8192 wave-groups
  int blocks = ngroups / 4;     // 2048 blocks of 4 waves

  taylor_mfma<<<blocks, 256, 0, stream>>>(x, W, b, out, ngroups);
}

// Round 10
// 17.246 us; speedup vs baseline: 1.0124x; 1.0124x over previous
//
#include <hip/hip_runtime.h>
#include <hip/hip_bf16.h>
#include <string.h>

// TaylorLayer via MFMA: out[B,8] = relu(W[8,164] @ epd[164,B] + b), B=262144.
// epd = monomials deg 1..3 of x[8], reference recursion order, T=164.
//
// Measured: fixed harness overhead ~10.5us (R6); best config R7 = 16.26us
// total (kernel ~5.8us vs 2.7us HBM floor). R9 showed in-kernel LDS prep
// is WORSE than the separate prep_w node.
//
// R10: two groups per wave. Work is exactly 8 waves/SIMD but occupancy is
// 4/SIMD -> R7 ran as 2 sequential batches, each paying ~900cyc HBM
// first-touch latency. Here: 4096 waves (one resident batch), each wave
// does adjacent groups g0,g1; both x-loads issued upfront (one latency
// exposure); g0's store overlaps g1's compute; afrag stream L1-hot on the
// second chain. Bias folded into MFMA (slot 84 = constant-1, W col = b in
// half0). No sched_barriers: scheduler may pull g1's muls under g0's MFMAs.
//
// Sigma trick (R7/R8): involution s(j)=j^4 maps the monomial set to
// itself; half-1 lanes run the IDENTICAL slot program on sigma-permuted
// inputs, absorbed into load addressing. W permuted to match (TDX).
//
// MFMA mfma_f32_32x32x16_bf16, K=176. A: row=lane&31 (rows 8..31 zero),
// half h=lane>>5, slot 8i+j (prep_w). B: col=lane&31, same k-map.
// C/D: col=lane&31, row=(reg&3)+8*(reg>>2)+4*(lane>>5) -> regs 0..3 =
// rows 4h+0..3 -> one float4 store per lane.

static constexpr int TEXP = 164;
static constexpr int NOUT = 8;
static constexpr int NMFMA = 11;   // K = 176
static constexpr int NSLOT = 88;   // slots per k-half
static constexpr int BIAS_T = 200; // marker: W entry = bias[row]
static constexpr int NWP = NMFMA * 64 * 8;  // 5632 entries

using f32x16 = __attribute__((ext_vector_type(16))) float;
using short8 = __attribute__((ext_vector_type(8))) short;

// ---- reference t-order index math ----
constexpr int rowstart2(int j) { return j * 8 - j * (j - 1) / 2; }
constexpr int start3(int j) {
  int s = 44;
  for (int jp = 0; jp < j; ++jp) s += (8 - jp) * (9 - jp) / 2;
  return s;
}
constexpr int t3_of(int a, int b, int c) {
  int x = a, y = b, z = c, t = 0;
  if (x > y) { t = x; x = y; y = t; }
  if (y > z) { t = y; y = z; z = t; }
  if (x > y) { t = x; x = y; y = t; }
  int off = 0;
  for (int ap = x; ap < y; ++ap) off += 8 - ap;
  return start3(x) + off + (z - y);
}

// ---- slot table: 84 half-0 representatives (>=2 low indices) + pads ----
struct Slot { int deg, a, b, c; };
struct SlotTable { Slot s[NSLOT]; };

constexpr bool isrep2(int j, int k) {      // j<=k
  if (k < 4) return true;
  if (j >= 4) return false;
  if (k == j + 4) return true;             // fixed (dup; W zero in half1)
  return j < k - 4;
}
constexpr bool isrep3(int a, int b, int c) {
  return ((a < 4) + (b < 4) + (c < 4)) >= 2;
}

constexpr SlotTable make_slots() {
  SlotTable T{};
  int s = 0;
  for (int j = 0; j < 4; ++j) T.s[s++] = {1, j, 0, 0};                 // 4
  for (int j = 0; j < 8; ++j)
    for (int k = j; k < 8; ++k)
      if (isrep2(j, k)) T.s[s++] = {2, j, k, 0};                       // 20
  for (int a = 0; a < 8; ++a)
    for (int b = a; b < 8; ++b)
      for (int c = b; c < 8; ++c)
        if (isrep3(a, b, c)) T.s[s++] = {3, a, b, c};                  // 60
  for (; s < NSLOT; ++s) T.s[s] = {0, 0, 0, 0};                        // 84..87
  return T;
}
constexpr SlotTable SLOTS = make_slots();

// ---- per-(half,slot) -> ref t index; -1 => W=0; BIAS_T => b[row] ----
struct TT { short t[2][NSLOT]; };
constexpr TT make_tt() {
  TT r{};
  for (int h = 0; h < 2; ++h)
    for (int s = 0; s < NSLOT; ++s) {
      Slot sl = SLOTS.s[s];
      int m = h ? 4 : 0;
      if (sl.deg == 0) {
        r.t[h][s] = (short)((h == 0 && s == 84) ? BIAS_T : -1);  // bias slot
      } else if (sl.deg == 1) {
        r.t[h][s] = (short)(sl.a ^ m);
      } else if (sl.deg == 2) {
        if (h == 1 && sl.b == (sl.a ^ 4)) { r.t[h][s] = -1; }    // dup-fixed
        else {
          int a = sl.a ^ m, b = sl.b ^ m;
          int lo = a < b ? a : b, hi2 = a < b ? b : a;
          r.t[h][s] = (short)(8 + rowstart2(lo) + (hi2 - lo));
        }
      } else {
        r.t[h][s] = (short)t3_of(sl.a ^ m, sl.b ^ m, sl.c ^ m);
      }
    }
  return r;
}
__device__ const TT TDX = make_tt();

__device__ __forceinline__ unsigned short bf16rne(float v) {
  union { float f; unsigned int u; } c; c.f = v;
  unsigned int u = c.u;
  return (unsigned short)((u + 0x7fffu + ((u >> 16) & 1u)) >> 16);
}

// slot value from sigma-permuted inputs xs and d2 over xs (rows j<4 only,
// 26 entries, indices 0..25). Slot 84 = constant-1 bias monomial.
template <int S>
__device__ __forceinline__ float slotval(const float (&xs)[8], const float (&d2)[26]) {
  constexpr int deg = SLOTS.s[S].deg;
  constexpr int a = SLOTS.s[S].a;
  constexpr int b = SLOTS.s[S].b;
  constexpr int c = SLOTS.s[S].c;
  if constexpr (deg == 1) return xs[a];
  else if constexpr (deg == 2) return d2[rowstart2(a) + (b - a)];         // a < 4
  else if constexpr (deg == 3) return xs[a] * d2[rowstart2(b) + (c - b)]; // b < 4
  else if constexpr (S == 84) return 1.0f;                                 // bias
  else return 0.0f;
}

template <int I>
struct MfmaStep {
  static __device__ __forceinline__ void run(const float (&xs)[8], const float (&d2)[26],
                                             const unsigned short* __restrict__ wpl,
                                             short8 af_cur, f32x16& acc) {
    short8 af_next;
    if constexpr (I + 1 < NMFMA)
      af_next = *reinterpret_cast<const short8*>(wpl + (I + 1) * 64 * 8);
    short8 bv;
    bv[0] = (short)bf16rne(slotval<8 * I + 0>(xs, d2));
    bv[1] = (short)bf16rne(slotval<8 * I + 1>(xs, d2));
    bv[2] = (short)bf16rne(slotval<8 * I + 2>(xs, d2));
    bv[3] = (short)bf16rne(slotval<8 * I + 3>(xs, d2));
    bv[4] = (short)bf16rne(slotval<8 * I + 4>(xs, d2));
    bv[5] = (short)bf16rne(slotval<8 * I + 5>(xs, d2));
    bv[6] = (short)bf16rne(slotval<8 * I + 6>(xs, d2));
    bv[7] = (short)bf16rne(slotval<8 * I + 7>(xs, d2));
    acc = __builtin_amdgcn_mfma_f32_32x32x16_bf16(af_cur, bv, acc, 0, 0, 0);
    if constexpr (I + 1 < NMFMA)
      MfmaStep<I + 1>::run(xs, d2, wpl, af_next, acc);
  }
};

// one full chain for one element: d2, MFMA chain, relu, store
__device__ __forceinline__ void chain(const float (&xs)[8],
                                      const unsigned short* __restrict__ wpl,
                                      float* __restrict__ dst) {
  float d2[26];
#pragma unroll
  for (int j = 0; j < 4; ++j) {
#pragma unroll
    for (int k = j; k < 8; ++k) {
      d2[rowstart2(j) + (k - j)] = xs[j] * xs[k];
    }
  }
  short8 af0 = *reinterpret_cast<const short8*>(wpl);
  f32x16 acc;
#pragma unroll
  for (int r = 0; r < 16; ++r) acc[r] = 0.0f;
  MfmaStep<0>::run(xs, d2, wpl, af0, acc);
  float4 o;  // bias already accumulated via slot 84
  o.x = fmaxf(acc[0], 0.0f);
  o.y = fmaxf(acc[1], 0.0f);
  o.z = fmaxf(acc[2], 0.0f);
  o.w = fmaxf(acc[3], 0.0f);
  *reinterpret_cast<float4*>(dst) = o;
}

// ---- prep: wp[(i*64+lane)*8 + j] = bf16(W[row][TDX[h][8i+j]]) ----
__global__ void prep_w(const float* __restrict__ W, const float* __restrict__ b,
                       unsigned short* __restrict__ wp) {
  int idx = threadIdx.x + blockIdx.x * blockDim.x;
  if (idx >= NWP) return;
  int j = idx & 7;
  int lane = (idx >> 3) & 63;
  int i = idx >> 9;
  int row = lane & 31, h = lane >> 5;
  int t = TDX.t[h][8 * i + j];
  float v = 0.0f;
  if (row < NOUT) {
    if (t >= 0 && t < TEXP) v = W[row * TEXP + t];
    else if (t == BIAS_T) v = b[row];
  }
  wp[idx] = bf16rne(v);
}

__global__ __launch_bounds__(256, 4) void taylor_mfma(
    const float* __restrict__ x, const unsigned short* __restrict__ wp,
    float* __restrict__ out, int ngroups) {
  const int lane = (int)(threadIdx.x & 63);
  const int h = (lane >= 32) ? 1 : 0;
  const int col = lane & 31;

  const int wave = (int)((blockIdx.x * blockDim.x + threadIdx.x) >> 6);
  const int g0 = wave * 2;
  if (g0 >= ngroups) return;

  const int elem0 = g0 * 32 + col;
  const int elem1 = elem0 + 32;

  // issue BOTH groups' x-loads upfront (one HBM latency exposure).
  // sigma absorbed into addressing: h=0 identity, h=1 swaps float4 halves.
  const float* xe0 = x + elem0 * 8;
  const float* xe1 = x + elem1 * 8;
  float4 a0 = *reinterpret_cast<const float4*>(xe0 + 4 * h);
  float4 b0 = *reinterpret_cast<const float4*>(xe0 + 4 - 4 * h);
  float4 a1 = *reinterpret_cast<const float4*>(xe1 + 4 * h);
  float4 b1 = *reinterpret_cast<const float4*>(xe1 + 4 - 4 * h);

  const unsigned short* wpl = wp + lane * 8;

  float xs0[8] = {a0.x, a0.y, a0.z, a0.w, b0.x, b0.y, b0.z, b0.w};
  chain(xs0, wpl, out + elem0 * 8 + 4 * h);

  float xs1[8] = {a1.x, a1.y, a1.z, a1.w, b1.x, b1.y, b1.z, b1.w};
  chain(xs1, wpl, out + elem1 * 8 + 4 * h);
}

extern "C" void kernel_launch(void* const* d_in, const int* in_sizes, int n_in,
                              void* d_out, int out_size, void* d_ws, size_t ws_size,
                              hipStream_t stream) {
  const float* x = (const float*)d_in[0];   // [262144, 8, 1]
  const float* W = (const float*)d_in[1];   // [8, 164]
  const float* b = (const float*)d_in[2];   // [8, 1]
  float* out = (float*)d_out;               // [262144, 8]
  unsigned short* wp = (unsigned short*)d_ws;  // 5632 bf16 = 11264 B

  int n = in_sizes[0] / 8;      // 262144 elements
  int ngroups = n / 32;         // 8192 wave-groups
  int blocks = ngroups / 8;     // 4 waves x 2 groups per block -> 1024

  prep_w<<<22, 256, 0, stream>>>(W, b, wp);
  taylor_mfma<<<blocks, 256, 0, stream>>>(x, wp, out, ngroups);
}

// Round 11
// 16.729 us; speedup vs baseline: 1.0437x; 1.0309x over previous
//
#include <hip/hip_runtime.h>
#include <hip/hip_bf16.h>
#include <string.h>

// TaylorLayer via MFMA: out[B,8] = relu(W[8,164] @ epd[164,B] + b), B=262144.
// epd = monomials deg 1..3 of x[8], reference recursion order, T=164.
//
// R11: 16x16x32 MFMA + Klein 4-group symmetry for 8 waves/SIMD occupancy.
//  - Group V = {id,^2,^4,^6} (XOR on variable indices) partitions the 164
//    monomials into 44 orbits. Lane-quarter q = lane>>4 runs an IDENTICAL
//    48-slot program (44 orbit reps + bias + 3 pads) on inputs permuted by
//    XOR m_q = 2q, absorbed into addressing (4 x float2 block loads,
//    block i <- block i^q). Coverage exact: 44*4 - 12 stabilizer dups
//    (W zeroed) = 164.
//  - All 30 deg-3 reps factor as x_e * (one of the 12 deg-2 rep products):
//    per-lane chain = 42 muls + ~43 casts (was 94 + 88).
//  - mfma_f32_16x16x32_bf16: acc = 4 VGPRs (was 16). Est live ~45 VGPR ->
//    __launch_bounds__(256,8): 8 waves/SIMD, whole grid resident (latency
//    was the residual: 5.8us kernel vs 2.4us VALU model at 4 waves/SIMD).
//  - A (Wperm) row=lane&15 (rows 8..15 zero), same per-quarter k-map as B
//    (A/B symmetry validated empirically for 32x32 in R3). C/D (m89/m91):
//    col=lane&15, row=(lane>>4)*4+reg -> quarters 0,1 store rows 0-3/4-7.

static constexpr int TEXP = 164;
static constexpr int NOUT = 8;
static constexpr int NMFMA = 6;    // K = 192 (4 quarters x 48 slots)
static constexpr int NSLOT = 48;   // slots per quarter
static constexpr int NPAIR = 12;
static constexpr int BIAS_T = 200; // marker: W entry = bias[row]
static constexpr int NWP = NMFMA * 64 * 8;  // 3072 entries

using f32x4 = __attribute__((ext_vector_type(4))) float;
using short8 = __attribute__((ext_vector_type(8))) short;

// ---- reference t-order index math ----
constexpr int rowstart2(int j) { return j * 8 - j * (j - 1) / 2; }
constexpr int start3(int j) {
  int s = 44;
  for (int jp = 0; jp < j; ++jp) s += (8 - jp) * (9 - jp) / 2;
  return s;
}
constexpr int t3_of(int a, int b, int c) {
  int x = a, y = b, z = c, t = 0;
  if (x > y) { t = x; x = y; y = t; }
  if (y > z) { t = y; y = z; z = t; }
  if (x > y) { t = x; x = y; y = t; }
  int off = 0;
  for (int ap = x; ap < y; ++ap) off += 8 - ap;
  return start3(x) + off + (z - y);
}

// ---- 12 deg-2 orbit-rep pairs (also the only deg-3 factors needed) ----
constexpr int PAIRA[NPAIR] = {0,1,0,1,0,1,0,1,0,0,0,0};
constexpr int PAIRB[NPAIR] = {0,1,2,3,4,5,6,7,1,3,5,7};

// ---- uniform 48-slot program: kind 0=x[a], 1=p[i], 2=x[a]*p[i], 3=1, 4=0
struct Prog { int kind, a, p; };
constexpr Prog PRG[NSLOT] = {
  {0,0,0},{0,1,0},                                  // deg-1 reps x0, x1
  {1,0,0},{1,0,1},{1,0,2},{1,0,3},{1,0,4},{1,0,5},  // deg-2 reps p0..p11
  {1,0,6},{1,0,7},{1,0,8},{1,0,9},{1,0,10},{1,0,11},
  // deg-3 reps (30): all-even
  {2,0,0},{2,2,0},{2,4,0},{2,6,0},{2,4,2},
  // all-odd
  {2,1,1},{2,3,1},{2,5,1},{2,7,1},{2,5,3},
  // 2-even 1-odd
  {2,1,0},{2,3,0},{2,5,0},{2,7,0},{2,2,8},{2,2,10},{2,4,8},{2,4,9},{2,6,8},{2,6,9},
  // 1-even 2-odd
  {2,1,8},{2,3,8},{2,5,8},{2,7,8},{2,3,9},{2,5,9},{2,7,9},{2,5,10},{2,7,10},{2,7,11},
  {3,0,0},                                          // bias (constant 1)
  {4,0,0},{4,0,0},{4,0,0}                           // pads
};

// ---- constexpr: slot s under quarter q -> sorted monomial multiset ----
struct MS { int n; int v[3]; };
constexpr MS slot_ms(int s, int q) {
  Prog g = PRG[s];
  int m = 2 * q;
  MS r{0, {0,0,0}};
  if (g.kind == 0) { r.n = 1; r.v[0] = g.a ^ m; }
  else if (g.kind == 1) { r.n = 2; r.v[0] = PAIRA[g.p] ^ m; r.v[1] = PAIRB[g.p] ^ m; }
  else if (g.kind == 2) {
    r.n = 3; r.v[0] = g.a ^ m; r.v[1] = PAIRA[g.p] ^ m; r.v[2] = PAIRB[g.p] ^ m;
  }
  for (int i = 0; i < r.n; ++i)
    for (int j = i + 1; j < r.n; ++j)
      if (r.v[j] < r.v[i]) { int t = r.v[i]; r.v[i] = r.v[j]; r.v[j] = t; }
  return r;
}
constexpr bool ms_eq(MS a, MS b) {
  if (a.n != b.n || a.n == 0) return false;
  for (int i = 0; i < a.n; ++i) if (a.v[i] != b.v[i]) return false;
  return true;
}
constexpr int ms_t(MS a) {
  if (a.n == 1) return a.v[0];
  if (a.n == 2) return 8 + rowstart2(a.v[0]) + (a.v[1] - a.v[0]);
  if (a.n == 3) return t3_of(a.v[0], a.v[1], a.v[2]);
  return -1;
}

// ---- per-(quarter, slot) -> ref t index; -1 => W=0; BIAS_T => b[row] ----
struct TT { short t[4][NSLOT]; };
constexpr TT make_tt() {
  TT r{};
  for (int q = 0; q < 4; ++q)
    for (int s = 0; s < NSLOT; ++s) {
      Prog g = PRG[s];
      if (g.kind == 3) { r.t[q][s] = (short)(q == 0 ? BIAS_T : -1); continue; }
      if (g.kind == 4) { r.t[q][s] = -1; continue; }
      MS ms = slot_ms(s, q);
      bool dup = false;
      for (int q2 = 0; q2 < q; ++q2)
        if (ms_eq(slot_ms(s, q2), ms)) dup = true;   // stabilizer duplicate
      r.t[q][s] = (short)(dup ? -1 : ms_t(ms));
    }
  return r;
}
__device__ const TT TDX = make_tt();

__device__ __forceinline__ unsigned short bf16rne(float v) {
  union { float f; unsigned int u; } c; c.f = v;
  unsigned int u = c.u;
  return (unsigned short)((u + 0x7fffu + ((u >> 16) & 1u)) >> 16);
}
__device__ __forceinline__ short bf16cast(float v) {
  __hip_bfloat16 h = __float2bfloat16(v);
  short s;
  memcpy(&s, &h, 2);
  return s;
}

template <int S>
__device__ __forceinline__ float slotval(const float (&xs)[8], const float (&p)[NPAIR]) {
  constexpr Prog g = PRG[S];
  if constexpr (g.kind == 0) return xs[g.a];
  else if constexpr (g.kind == 1) return p[g.p];
  else if constexpr (g.kind == 2) return xs[g.a] * p[g.p];
  else if constexpr (g.kind == 3) return 1.0f;
  else return 0.0f;
}

template <int I>
struct MfmaStep {
  static __device__ __forceinline__ void run(const float (&xs)[8], const float (&p)[NPAIR],
                                             const unsigned short* __restrict__ wpl,
                                             short8 af_cur, f32x4& acc) {
    short8 af_next;
    if constexpr (I + 1 < NMFMA)
      af_next = *reinterpret_cast<const short8*>(wpl + (I + 1) * 64 * 8);
    short8 bv;
    bv[0] = bf16cast(slotval<8 * I + 0>(xs, p));
    bv[1] = bf16cast(slotval<8 * I + 1>(xs, p));
    bv[2] = bf16cast(slotval<8 * I + 2>(xs, p));
    bv[3] = bf16cast(slotval<8 * I + 3>(xs, p));
    bv[4] = bf16cast(slotval<8 * I + 4>(xs, p));
    bv[5] = bf16cast(slotval<8 * I + 5>(xs, p));
    bv[6] = bf16cast(slotval<8 * I + 6>(xs, p));
    bv[7] = bf16cast(slotval<8 * I + 7>(xs, p));
    acc = __builtin_amdgcn_mfma_f32_16x16x32_bf16(af_cur, bv, acc, 0, 0, 0);
    if constexpr (I + 1 < NMFMA)
      MfmaStep<I + 1>::run(xs, p, wpl, af_next, acc);
  }
};

// one chain: load 16-elem group's x (XOR-block addressing), 12 pair muls,
// 6 MFMAs, quarters 0/1 store rows 0-3 / 4-7.
__device__ __forceinline__ void chain(const float* __restrict__ xe, int q,
                                      const unsigned short* __restrict__ wpl,
                                      float* __restrict__ dst, bool st) {
  float2 B0 = *reinterpret_cast<const float2*>(xe + ((0 ^ q) * 2));
  float2 B1 = *reinterpret_cast<const float2*>(xe + ((1 ^ q) * 2));
  float2 B2 = *reinterpret_cast<const float2*>(xe + ((2 ^ q) * 2));
  float2 B3 = *reinterpret_cast<const float2*>(xe + ((3 ^ q) * 2));
  float xs[8] = {B0.x, B0.y, B1.x, B1.y, B2.x, B2.y, B3.x, B3.y};

  float p[NPAIR];
#pragma unroll
  for (int i = 0; i < NPAIR; ++i) p[i] = xs[PAIRA[i]] * xs[PAIRB[i]];

  short8 af0 = *reinterpret_cast<const short8*>(wpl);
  f32x4 acc = {0.0f, 0.0f, 0.0f, 0.0f};
  MfmaStep<0>::run(xs, p, wpl, af0, acc);

  if (st) {
    float4 o;  // bias accumulated via slot 44
    o.x = fmaxf(acc[0], 0.0f);
    o.y = fmaxf(acc[1], 0.0f);
    o.z = fmaxf(acc[2], 0.0f);
    o.w = fmaxf(acc[3], 0.0f);
    *reinterpret_cast<float4*>(dst) = o;
  }
}

// ---- prep: wp[(i*64+lane)*8 + j] = bf16(W[row][TDX[q][8i+j]]),
// row=lane&15 (>=8 -> 0), q=lane>>4; BIAS_T -> b[row]; -1 -> 0 ----
__global__ void prep_w(const float* __restrict__ W, const float* __restrict__ b,
                       unsigned short* __restrict__ wp) {
  int idx = threadIdx.x + blockIdx.x * blockDim.x;
  if (idx >= NWP) return;
  int j = idx & 7;
  int lane = (idx >> 3) & 63;
  int i = idx >> 9;
  int row = lane & 15, q = lane >> 4;
  int t = TDX.t[q][8 * i + j];
  float v = 0.0f;
  if (row < NOUT) {
    if (t >= 0 && t < TEXP) v = W[row * TEXP + t];
    else if (t == BIAS_T) v = b[row];
  }
  wp[idx] = bf16rne(v);
}

__global__ __launch_bounds__(256, 8) void taylor_mfma(
    const float* __restrict__ x, const unsigned short* __restrict__ wp,
    float* __restrict__ out) {
  const int lane = (int)(threadIdx.x & 63);
  const int q = lane >> 4;
  const int col = lane & 15;
  const bool st = q < 2;
  const int ro = (q & 1) * 4;  // store row offset: q0 -> rows 0-3, q1 -> 4-7

  const int wave = (int)((blockIdx.x * blockDim.x + threadIdx.x) >> 6);
  const int elem0 = wave * 32 + col;  // chain 0: elements [wave*32, +16)
  const int elem1 = elem0 + 16;       // chain 1

  const unsigned short* wpl = wp + lane * 8;

  chain(x + elem0 * 8, q, wpl, out + elem0 * 8 + ro, st);
  chain(x + elem1 * 8, q, wpl, out + elem1 * 8 + ro, st);
}

extern "C" void kernel_launch(void* const* d_in, const int* in_sizes, int n_in,
                              void* d_out, int out_size, void* d_ws, size_t ws_size,
                              hipStream_t stream) {
  const float* x = (const float*)d_in[0];   // [262144, 8, 1]
  const float* W = (const float*)d_in[1];   // [8, 164]
  const float* b = (const float*)d_in[2];   // [8, 1]
  float* out = (float*)d_out;               // [262144, 8]
  unsigned short* wp = (unsigned short*)d_ws;  // 3072 bf16 = 6144 B

  int n = in_sizes[0] / 8;      // 262144 elements
  int blocks = n / 128;         // 4 waves x 32 elems per block -> 2048

  prep_w<<<12, 256, 0, stream>>>(W, b, wp);
  taylor_mfma<<<blocks, 256, 0, stream>>>(x, wp, out);
}

// Round 13
// 16.248 us; speedup vs baseline: 1.0746x; 1.0296x over previous
//
#include <hip/hip_runtime.h>
#include <hip/hip_bf16.h>
#include <string.h>

// TaylorLayer via MFMA: out[B,8] = relu(W[8,164] @ epd[164,B] + b), B=262144.
// epd = monomials deg 1..3 of x[8], reference recursion order, T=164.
//
// R13 = R12 with the compile fix: __builtin_nontemporal_{load,store}
// requires scalar/ext-vector pointers, not HIP_vector_type structs ->
// use ext_vector float4 (fx4) for the NT-touched x/out accesses.
// Hypothesis unchanged: out (8MB) is write-once -> NT store bypasses L2
// write-allocate; x (8MB) read-once -> NT load skips dead L2 insertions.
// Base = R7 (best measured 16.26us).
//
// Sigma trick (R7): involution s(j)=j^4 maps the monomial set to itself
// (4 fixed: x_j*x_{j+4}; 80 2-orbits). Half-0 lanes compute orbit reps;
// half-1 lanes run the IDENTICAL slot program on sigma-permuted inputs
// (8 cndmask), since sigma(m)(x) = m(sigma(x)). W permuted to match (TDX).
//
// MFMA mfma_f32_32x32x16_bf16, K=176. A: row=lane&31 (rows 8..31 zero),
// half h=lane>>5, slot 8i+j (prep_w). B: col=lane&31, same k-map.
// C/D: col=lane&31, row=(reg&3)+8*(reg>>2)+4*(lane>>5) -> regs 0..3 =
// rows 4h+0..3 -> one float4 store per lane.

static constexpr int TEXP = 164;
static constexpr int NOUT = 8;
static constexpr int NMFMA = 11;   // K = 176
static constexpr int NSLOT = 88;   // slots per k-half

using f32x16 = __attribute__((ext_vector_type(16))) float;
using short8 = __attribute__((ext_vector_type(8))) short;
using fx4 = __attribute__((ext_vector_type(4))) float;  // NT-compatible

// ---- reference t-order index math ----
constexpr int rowstart2(int j) { return j * 8 - j * (j - 1) / 2; }
constexpr int start3(int j) {
  int s = 44;
  for (int jp = 0; jp < j; ++jp) s += (8 - jp) * (9 - jp) / 2;
  return s;
}
constexpr int t3_of(int a, int b, int c) {
  int x = a, y = b, z = c, t = 0;
  if (x > y) { t = x; x = y; y = t; }
  if (y > z) { t = y; y = z; z = t; }
  if (x > y) { t = x; x = y; y = t; }
  int off = 0;
  for (int ap = x; ap < y; ++ap) off += 8 - ap;
  return start3(x) + off + (z - y);
}

// ---- slot table: 88 half-0 representatives (>=2 low indices) ----
struct Slot { int deg, a, b, c; };
struct SlotTable { Slot s[NSLOT]; };

constexpr bool isrep2(int j, int k) {      // j<=k
  if (k < 4) return true;
  if (j >= 4) return false;
  if (k == j + 4) return true;             // fixed (dup; W zero in half1)
  return j < k - 4;
}
constexpr bool isrep3(int a, int b, int c) {
  return ((a < 4) + (b < 4) + (c < 4)) >= 2;
}

constexpr SlotTable make_slots() {
  SlotTable T{};
  int s = 0;
  for (int j = 0; j < 4; ++j) T.s[s++] = {1, j, 0, 0};                 // 4
  for (int j = 0; j < 8; ++j)
    for (int k = j; k < 8; ++k)
      if (isrep2(j, k)) T.s[s++] = {2, j, k, 0};                       // 20
  for (int a = 0; a < 8; ++a)
    for (int b = a; b < 8; ++b)
      for (int c = b; c < 8; ++c)
        if (isrep3(a, b, c)) T.s[s++] = {3, a, b, c};                  // 60
  for (; s < NSLOT; ++s) T.s[s] = {0, 0, 0, 0};                        // 4 pads
  return T;
}
constexpr SlotTable SLOTS = make_slots();

// ---- per-(half,slot) -> reference t index (or -1 => W = 0) ----
struct TT { short t[2][NSLOT]; };
constexpr TT make_tt() {
  TT r{};
  for (int h = 0; h < 2; ++h)
    for (int s = 0; s < NSLOT; ++s) {
      Slot sl = SLOTS.s[s];
      int m = h ? 4 : 0;
      if (sl.deg == 0) { r.t[h][s] = -1; }
      else if (sl.deg == 1) { r.t[h][s] = (short)(sl.a ^ m); }
      else if (sl.deg == 2) {
        if (h == 1 && sl.b == (sl.a ^ 4)) { r.t[h][s] = -1; }
        else {
          int a = sl.a ^ m, b = sl.b ^ m;
          int lo = a < b ? a : b, hi2 = a < b ? b : a;
          r.t[h][s] = (short)(8 + rowstart2(lo) + (hi2 - lo));
        }
      } else {
        r.t[h][s] = (short)t3_of(sl.a ^ m, sl.b ^ m, sl.c ^ m);
      }
    }
  return r;
}
__device__ const TT TDX = make_tt();

__device__ __forceinline__ short bf16bits(float v) {
  __hip_bfloat16 h = __float2bfloat16(v);
  short s;
  memcpy(&s, &h, 2);
  return s;
}

// slot value from sigma-permuted inputs xs and d2 over xs (rows j<4)
template <int S>
__device__ __forceinline__ float slotval(const float (&xs)[8], const float (&d2)[36]) {
  constexpr int deg = SLOTS.s[S].deg;
  constexpr int a = SLOTS.s[S].a;
  constexpr int b = SLOTS.s[S].b;
  constexpr int c = SLOTS.s[S].c;
  if constexpr (deg == 1) return xs[a];
  else if constexpr (deg == 2) return d2[rowstart2(a) + (b - a)];         // a < 4
  else if constexpr (deg == 3) return xs[a] * d2[rowstart2(b) + (c - b)]; // b < 4
  else return 0.0f;
}

template <int I>
struct MfmaStep {
  static __device__ __forceinline__ void run(const float (&xs)[8], const float (&d2)[36],
                                             const unsigned short* __restrict__ wpl,
                                             short8 af_cur, f32x16& acc) {
    short8 af_next;
    if constexpr (I + 1 < NMFMA)
      af_next = *reinterpret_cast<const short8*>(wpl + (I + 1) * 64 * 8);
    short8 bv;
    bv[0] = bf16bits(slotval<8 * I + 0>(xs, d2));
    bv[1] = bf16bits(slotval<8 * I + 1>(xs, d2));
    bv[2] = bf16bits(slotval<8 * I + 2>(xs, d2));
    bv[3] = bf16bits(slotval<8 * I + 3>(xs, d2));
    bv[4] = bf16bits(slotval<8 * I + 4>(xs, d2));
    bv[5] = bf16bits(slotval<8 * I + 5>(xs, d2));
    bv[6] = bf16bits(slotval<8 * I + 6>(xs, d2));
    bv[7] = bf16bits(slotval<8 * I + 7>(xs, d2));
    acc = __builtin_amdgcn_mfma_f32_32x32x16_bf16(af_cur, bv, acc, 0, 0, 0);
    __builtin_amdgcn_sched_barrier(0);
    if constexpr (I + 1 < NMFMA)
      MfmaStep<I + 1>::run(xs, d2, wpl, af_next, acc);
  }
};

// ---- prep: wp[(i*64+lane)*8 + j] = bf16(W[row][ TDX[h][8i+j] ]) ----
__global__ void prep_w(const float* __restrict__ W, unsigned short* __restrict__ wp) {
  int idx = threadIdx.x + blockIdx.x * blockDim.x;
  if (idx >= NMFMA * 64 * 8) return;
  int j = idx & 7;
  int lane = (idx >> 3) & 63;
  int i = idx >> 9;
  int row = lane & 31, h = lane >> 5;
  int t = TDX.t[h][8 * i + j];
  float v = (row < NOUT && t >= 0) ? W[row * TEXP + t] : 0.0f;
  union { float f; unsigned int u; } c; c.f = v;
  unsigned int u = c.u;
  wp[idx] = (unsigned short)((u + 0x7fffu + ((u >> 16) & 1u)) >> 16);  // RNE
}

__global__ __launch_bounds__(256, 4) void taylor_mfma(
    const float* __restrict__ x, const float* __restrict__ b,
    const unsigned short* __restrict__ wp, float* __restrict__ out, int ngroups) {
  const int lane = (int)(threadIdx.x & 63);
  const bool hi = lane >= 32;
  const int h = hi ? 1 : 0;
  const int col = lane & 31;

  const unsigned short* wpl = wp + lane * 8;
  short8 af0 = *reinterpret_cast<const short8*>(wpl);

  const float4 bv4 = *reinterpret_cast<const float4*>(b + 4 * h);

  const int g = (int)((blockIdx.x * blockDim.x + threadIdx.x) >> 6);
  if (g >= ngroups) return;

  const int elem = g * 32 + col;
  // non-temporal x loads (ext-vector type): read-once stream
  fx4 xa = __builtin_nontemporal_load(reinterpret_cast<const fx4*>(x) + elem * 2 + 0);
  fx4 xb = __builtin_nontemporal_load(reinterpret_cast<const fx4*>(x) + elem * 2 + 1);
  float xv[8] = {xa[0], xa[1], xa[2], xa[3], xb[0], xb[1], xb[2], xb[3]};

  // half-1 lanes permute inputs by sigma (j ^ 4): slot program is then
  // identical for both halves.
  float xs[8];
#pragma unroll
  for (int j = 0; j < 8; ++j) xs[j] = hi ? xv[j ^ 4] : xv[j];

  // d2 over xs, rows j<4 only (all slot reps have a low pair-lead)
  float d2[36];
#pragma unroll
  for (int j = 0; j < 4; ++j) {
#pragma unroll
    for (int k = j; k < 8; ++k) {
      d2[rowstart2(j) + (k - j)] = xs[j] * xs[k];
    }
  }

  f32x16 acc;
#pragma unroll
  for (int r = 0; r < 16; ++r) acc[r] = 0.0f;

  MfmaStep<0>::run(xs, d2, wpl, af0, acc);

  fx4 o;
  o[0] = fmaxf(acc[0] + bv4.x, 0.0f);
  o[1] = fmaxf(acc[1] + bv4.y, 0.0f);
  o[2] = fmaxf(acc[2] + bv4.z, 0.0f);
  o[3] = fmaxf(acc[3] + bv4.w, 0.0f);
  // non-temporal store: write-once stream, bypass L2 write-allocate
  __builtin_nontemporal_store(o, reinterpret_cast<fx4*>(out + elem * 8 + 4 * h));
}

extern "C" void kernel_launch(void* const* d_in, const int* in_sizes, int n_in,
                              void* d_out, int out_size, void* d_ws, size_t ws_size,
                              hipStream_t stream) {
  const float* x = (const float*)d_in[0];   // [262144, 8, 1]
  const float* W = (const float*)d_in[1];   // [8, 164]
  const float* b = (const float*)d_in[2];   // [8, 1]
  float* out = (float*)d_out;               // [262144, 8]
  unsigned short* wp = (unsigned short*)d_ws;  // 5632 bf16 = 11264 B

  int n = in_sizes[0] / 8;      // 262144 elements
  int ngroups = n / 32;         // 8192 wave-groups
  int blocks = ngroups / 4;     // 2048 blocks of 4 waves

  prep_w<<<22, 256, 0, stream>>>(W, wp);
  taylor_mfma<<<blocks, 256, 0, stream>>>(x, b, wp, out, ngroups);
}